// Round 10
// baseline (150.200 us; speedup 1.0000x reference)
//
#include <hip/hip_runtime.h>
#include <math.h>

#define WH     256
#define NDEPTH 8
#define NBATCH 1024
#define NB     4            // batch elements per block (512 blocks)
#define PLANE  (WH * WH)    // 65536

typedef _Float16 h2 __attribute__((ext_vector_type(2)));

// ws layout (fp16): wsh[arr][hq][d][hs][w]
//   arr: 0=M1 1=B1 2=M2 3=B2 ; hq = h>>6 ; hs = h&63
// Per (arr,hq): 8*64*256 halfs = 256 KB, contiguous across depth ->
// each prop wave streams one pointer with +2 KB per 4-row chunk.
#define HQBLK  (NDEPTH * 64 * WH)   // halfs per (arr,hq) block = 131072

// ---------------------------------------------------------------------------
// Transpose + fp32->fp16 convert. 512 blocks x 256 threads. (~10us, unchanged)
// ---------------------------------------------------------------------------
__global__ __launch_bounds__(256) void transpose_half_k(const float* __restrict__ M1,
                                                        const float* __restrict__ B1,
                                                        const float* __restrict__ M2,
                                                        const float* __restrict__ B2,
                                                        _Float16* __restrict__ wsh) {
    __shared__ float tile[64][65];
    const int bid = blockIdx.x;
    const int arr = bid >> 7;
    const int d   = (bid >> 4) & 7;
    const int ht  = (bid >> 2) & 3;     // h-tile == hq
    const int wt  = bid & 3;            // w-tile

    const float* src = (arr == 0) ? M1 : (arr == 1) ? B1 : (arr == 2) ? M2 : B2;
    const float* s = src + d * PLANE;
    _Float16* o = wsh + ((size_t)(arr * 4 + ht) * NDEPTH + d) * (64 * WH);

    const int t   = threadIdx.x;
    const int q16 = t >> 4;     // 0..15
    const int r16 = t & 15;     // 0..15

#pragma unroll
    for (int p = 0; p < 4; ++p) {        // read: float4 along h ([d][w][h])
        const int wrow = q16 + p * 16;
        const float4 v = *(const float4*)(s + (wt * 64 + wrow) * WH + ht * 64 + r16 * 4);
        tile[wrow][r16 * 4 + 0] = v.x;
        tile[wrow][r16 * 4 + 1] = v.y;
        tile[wrow][r16 * 4 + 2] = v.z;
        tile[wrow][r16 * 4 + 3] = v.w;
    }
    __syncthreads();
#pragma unroll
    for (int p = 0; p < 4; ++p) {        // write: 4 halfs along w
        const int hrow = q16 + p * 16;
        const int wl   = r16 * 4;
        union { _Float16 f[4]; uint2 u; } pk;
        pk.f[0] = (_Float16)tile[wl + 0][hrow];
        pk.f[1] = (_Float16)tile[wl + 1][hrow];
        pk.f[2] = (_Float16)tile[wl + 2][hrow];
        pk.f[3] = (_Float16)tile[wl + 3][hrow];
        *(uint2*)(o + hrow * WH + wt * 64 + wl) = pk.u;
    }
}

// ---------------------------------------------------------------------------
// Prop: 512 blocks x 256 threads, __launch_bounds__(256, 2).
// *** Occupancy lore (R6-R10): VGPR=168 -> HW runs only 1 block/CU (10.9%).
// *** (256,2) clamps VGPR to 128 and enables 2 blocks/CU (21%, R7) — but the
// *** live set must FIT 128 or it spills (R7: 286MB scratch). This version
// *** uses a 2-slot double buffer (32 buf VGPRs, live set ~100) to fit.
// bid&7 -> XCD; br = (bid&7)>>2 (one branch's 2 MiB per XCD L2).
// Wave owns 64 h (hq=wave). Chunk = 4 rows = 128 uint4; lane loads +lane,
// +64+lane. Distance-1 prefetch, running pointers, contiguous across depths.
// Math: v_pk_fma_f16 + v_pk_max_f16 (1 VALU instr / element).
// ---------------------------------------------------------------------------
__global__ __launch_bounds__(256, 2) void prop_h_k(const _Float16* __restrict__ wsh,
                                                   const float* __restrict__ val,
                                                   float* __restrict__ out) {
    const int bid  = blockIdx.x;
    const int x    = bid & 7;             // XCD hint
    const int br   = x >> 2;
    const int bg   = (bid >> 3) * 4 + (x & 3);   // 0..255
    const int t    = threadIdx.x;
    const int wave = t >> 6;              // 0..3 = hq
    const int lane = t & 63;

    const int arrM = br ? 2 : 0;
    const int arrB = br ? 3 : 1;
    // uint4 units: HQBLK/8 = 16384 uint4 per (arr,hq); chunk = 128 uint4
    const uint4* __restrict__ mp = (const uint4*)wsh + (size_t)(arrM * 4 + wave) * (HQBLK / 8) + lane;
    const uint4* __restrict__ bp = (const uint4*)wsh + (size_t)(arrB * 4 + wave) * (HQBLK / 8) + lane;

    h2 q2[NB];
#pragma unroll
    for (int nb = 0; nb < NB; ++nb) {
        const _Float16 qh = (_Float16)val[bg * NB + nb];   // block-uniform
        q2[nb].x = qh; q2[nb].y = qh;
    }

    __shared__ h2 part[8][NB][128];   // 8 KB: [virtual wave][nb][w/2]
    __shared__ float qs[NB];

    union H8 { uint4 u; h2 h[4]; };

    // 2-slot double buffer: 8 uint4 = 32 VGPRs of prefetch state
    uint4 bm[2][2], bb[2][2];
    bm[0][0] = mp[0]; bm[0][1] = mp[64];
    bb[0][0] = bp[0]; bb[0][1] = bp[64];
    mp += 128; bp += 128;

    union { unsigned short us; _Float16 f; } ninf; ninf.us = 0xFC00;  // -inf
    h2 NEGINF; NEGINF.x = ninf.f; NEGINF.y = ninf.f;

    for (int d = 0; d < NDEPTH; ++d) {
        h2 acc[NB][4];
#pragma unroll
        for (int nb = 0; nb < NB; ++nb)
#pragma unroll
            for (int k = 0; k < 4; ++k) acc[nb][k] = NEGINF;

#pragma unroll
        for (int c = 0; c < 16; ++c) {
            const int cur = c & 1, nxt = cur ^ 1;
            if (d * 16 + c + 1 < NDEPTH * 16) {    // prefetch next chunk
                bm[nxt][0] = mp[0]; bm[nxt][1] = mp[64];
                bb[nxt][0] = bp[0]; bb[nxt][1] = bp[64];
                mp += 128; bp += 128;
            }
            H8 m0, m1, b0, b1;
            m0.u = bm[cur][0]; m1.u = bm[cur][1];
            b0.u = bb[cur][0]; b1.u = bb[cur][1];
#pragma unroll
            for (int nb = 0; nb < NB; ++nb) {
                const h2 qq = q2[nb];
#pragma unroll
                for (int k = 0; k < 4; ++k) {
                    acc[nb][k] = __builtin_elementwise_max(
                        acc[nb][k], __builtin_elementwise_fma(qq, m0.h[k], b0.h[k]));
                    acc[nb][k] = __builtin_elementwise_max(
                        acc[nb][k], __builtin_elementwise_fma(qq, m1.h[k], b1.h[k]));
                }
            }
        }

        // stage partials: vw = distinct 32-h subset, j32 owns w = j32*8..+7
        const int vw  = wave * 2 + (lane >> 5);
        const int j32 = lane & 31;
#pragma unroll
        for (int nb = 0; nb < NB; ++nb) {
            H8 st;
            st.h[0] = acc[nb][0]; st.h[1] = acc[nb][1];
            st.h[2] = acc[nb][2]; st.h[3] = acc[nb][3];
            *(uint4*)&part[vw][nb][j32 * 4] = st.u;
        }
        __syncthreads();

        // reduce on waves 0-1: nb = t>>5 (0..3), j = t&31
        if (t < 128) {
            const int nb = t >> 5;
            const int j  = t & 31;
            H8 v; v.u = *(const uint4*)&part[0][nb][j * 4];
#pragma unroll
            for (int s2 = 1; s2 < 8; ++s2) {
                H8 w2; w2.u = *(const uint4*)&part[s2][nb][j * 4];
#pragma unroll
                for (int k = 0; k < 4; ++k)
                    v.h[k] = __builtin_elementwise_max(v.h[k], w2.h[k]);
            }
            h2 mn = __builtin_elementwise_min(
                        __builtin_elementwise_min(v.h[0], v.h[1]),
                        __builtin_elementwise_min(v.h[2], v.h[3]));
            float r = fminf((float)mn.x, (float)mn.y);
#pragma unroll
            for (int off = 16; off > 0; off >>= 1)
                r = fminf(r, __shfl_xor(r, off, 32));
            if (j == 0) qs[nb] = r;
        }
        __syncthreads();
#pragma unroll
        for (int nb = 0; nb < NB; ++nb) {
            const _Float16 qh = (_Float16)qs[nb];
            q2[nb].x = qh; q2[nb].y = qh;
        }
        // part[] rewritten only after this barrier next depth -> safe
    }

    if (t < NB) out[br * NBATCH + bg * NB + t] = qs[t];
}

// ---------------------------------------------------------------------------
extern "C" void kernel_launch(void* const* d_in, const int* in_sizes, int n_in,
                              void* d_out, int out_size, void* d_ws, size_t ws_size,
                              hipStream_t stream) {
    const float* val = (const float*)d_in[0];
    const float* M1  = (const float*)d_in[1];
    const float* B1  = (const float*)d_in[2];
    const float* M2  = (const float*)d_in[3];
    const float* B2  = (const float*)d_in[4];
    float*    out = (float*)d_out;
    _Float16* wsh = (_Float16*)d_ws;   // 4 MiB (ws >= 8 MiB verified R2)

    transpose_half_k<<<dim3(512), dim3(256), 0, stream>>>(M1, B1, M2, B2, wsh);
    prop_h_k<<<dim3(512), dim3(256), 0, stream>>>(wsh, val, out);
}

// Round 11
// 113.941 us; speedup vs baseline: 1.3182x; 1.3182x over previous
//
#include <hip/hip_runtime.h>
#include <math.h>

#define WH     256
#define NDEPTH 8
#define NBATCH 1024
#define NB     8            // batch elements per block (256 blocks, 1/CU)
#define PLANE  (WH * WH)    // 65536

typedef _Float16 h2 __attribute__((ext_vector_type(2)));

// ws layout (fp16): wsh[arr][hq][d][hs][w]
//   arr: 0=M1 1=B1 2=M2 3=B2 ; hq = h>>6 ; hs = h&63
// Per (arr,hq): 8*64*256 halfs = 256 KB, contiguous across depth ->
// each prop wave streams ONE pointer, +2 KB per 4-row chunk, branchless.
// The pipeline over-reads up to 3 chunks (6 KB) past its stream end; all
// streams are interior to the 4 MiB ws except the last, which over-reads
// into d_ws tail (ws_size >= 8 MiB, verified R2) -> harmless.
#define HQBLK  (NDEPTH * 64 * WH)   // halfs per (arr,hq) block = 131072

// ---------------------------------------------------------------------------
// Transpose + fp32->fp16 convert. 512 blocks x 256 threads. (~10us, unchanged)
// ---------------------------------------------------------------------------
__global__ __launch_bounds__(256) void transpose_half_k(const float* __restrict__ M1,
                                                        const float* __restrict__ B1,
                                                        const float* __restrict__ M2,
                                                        const float* __restrict__ B2,
                                                        _Float16* __restrict__ wsh) {
    __shared__ float tile[64][65];
    const int bid = blockIdx.x;
    const int arr = bid >> 7;
    const int d   = (bid >> 4) & 7;
    const int ht  = (bid >> 2) & 3;     // h-tile == hq
    const int wt  = bid & 3;            // w-tile

    const float* src = (arr == 0) ? M1 : (arr == 1) ? B1 : (arr == 2) ? M2 : B2;
    const float* s = src + d * PLANE;
    _Float16* o = wsh + ((size_t)(arr * 4 + ht) * NDEPTH + d) * (64 * WH);

    const int t   = threadIdx.x;
    const int q16 = t >> 4;     // 0..15
    const int r16 = t & 15;     // 0..15

#pragma unroll
    for (int p = 0; p < 4; ++p) {        // read: float4 along h ([d][w][h])
        const int wrow = q16 + p * 16;
        const float4 v = *(const float4*)(s + (wt * 64 + wrow) * WH + ht * 64 + r16 * 4);
        tile[wrow][r16 * 4 + 0] = v.x;
        tile[wrow][r16 * 4 + 1] = v.y;
        tile[wrow][r16 * 4 + 2] = v.z;
        tile[wrow][r16 * 4 + 3] = v.w;
    }
    __syncthreads();
#pragma unroll
    for (int p = 0; p < 4; ++p) {        // write: 4 halfs along w
        const int hrow = q16 + p * 16;
        const int wl   = r16 * 4;
        union { _Float16 f[4]; uint2 u; } pk;
        pk.f[0] = (_Float16)tile[wl + 0][hrow];
        pk.f[1] = (_Float16)tile[wl + 1][hrow];
        pk.f[2] = (_Float16)tile[wl + 2][hrow];
        pk.f[3] = (_Float16)tile[wl + 3][hrow];
        *(uint2*)(o + hrow * WH + wt * 64 + wl) = pk.u;
    }
}

// ---------------------------------------------------------------------------
// Prop: 256 blocks x 256 threads, NB=8 (best measured shape, R6: 70us).
// *** Occupancy lore (R6-R10): this kernel cannot fit 128 VGPR without
// *** spilling (~150-300MB scratch, R7/R10), so 2-blocks/CU is unreachable;
// *** run 1 block/CU with VGPR~170 and win via in-wave pipelining instead.
// *** Plain __launch_bounds__(256): any min-waves arg >=2 clamps VGPR->spill.
// Change vs R6: prefetch is BRANCHLESS (R6's guarded prefetch blocked load
// hoisting -> effective distance ~0 -> 58% latency idle). 4-slot ring,
// distance 3, running pointers, streams contiguous across depths.
// Math: v_pk_fma_f16 + v_pk_max_f16 (1 VALU instr / element).
// ---------------------------------------------------------------------------
__global__ __launch_bounds__(256) void prop_h_k(const _Float16* __restrict__ wsh,
                                                const float* __restrict__ val,
                                                float* __restrict__ out) {
    const int bid  = blockIdx.x;
    const int x    = bid & 7;             // XCD hint
    const int br   = x >> 2;              // branch -> XCD half
    const int bg   = (bid >> 3) * 4 + (x & 3);   // 0..127
    const int t    = threadIdx.x;
    const int wave = t >> 6;              // 0..3 = hq
    const int lane = t & 63;

    const int arrM = br ? 2 : 0;
    const int arrB = br ? 3 : 1;
    // uint4 units: HQBLK/8 = 16384 uint4 per (arr,hq); chunk = 128 uint4
    const uint4* __restrict__ mp = (const uint4*)wsh + (size_t)(arrM * 4 + wave) * (HQBLK / 8) + lane;
    const uint4* __restrict__ bp = (const uint4*)wsh + (size_t)(arrB * 4 + wave) * (HQBLK / 8) + lane;

    h2 q2[NB];
#pragma unroll
    for (int nb = 0; nb < NB; ++nb) {
        const _Float16 qh = (_Float16)val[bg * NB + nb];   // block-uniform
        q2[nb].x = qh; q2[nb].y = qh;
    }

    __shared__ h2 part[8][NB][128];   // 32 KB: [virtual wave][nb][w/2]
    __shared__ float qs[NB];

    union H8 { uint4 u; h2 h[4]; };

    // 4-slot ring, 16 uint4 = 64 VGPRs of prefetch state (fits at 1 block/CU)
    uint4 bm[4][2], bb[4][2];
#pragma unroll
    for (int s = 0; s < 3; ++s) {          // prologue: chunks 0..2
        bm[s][0] = mp[0]; bm[s][1] = mp[64];
        bb[s][0] = bp[0]; bb[s][1] = bp[64];
        mp += 128; bp += 128;
    }

    union { unsigned short us; _Float16 f; } ninf; ninf.us = 0xFC00;  // -inf
    h2 NEGINF; NEGINF.x = ninf.f; NEGINF.y = ninf.f;

    for (int d = 0; d < NDEPTH; ++d) {
        h2 acc[NB][4];
#pragma unroll
        for (int nb = 0; nb < NB; ++nb)
#pragma unroll
            for (int k = 0; k < 4; ++k) acc[nb][k] = NEGINF;

#pragma unroll
        for (int c = 0; c < 16; ++c) {
            const int slot = c & 3;          // compile-time per unrolled iter
            const int ps   = (c + 3) & 3;
            // BRANCHLESS prefetch: may over-read <=6 KB past stream end,
            // stays inside d_ws (>=8 MiB; fp16 ws is 4 MiB). Values unused.
            bm[ps][0] = mp[0]; bm[ps][1] = mp[64];
            bb[ps][0] = bp[0]; bb[ps][1] = bp[64];
            mp += 128; bp += 128;

            H8 m0, m1, b0, b1;
            m0.u = bm[slot][0]; m1.u = bm[slot][1];
            b0.u = bb[slot][0]; b1.u = bb[slot][1];
#pragma unroll
            for (int nb = 0; nb < NB; ++nb) {
                const h2 qq = q2[nb];
#pragma unroll
                for (int k = 0; k < 4; ++k) {
                    acc[nb][k] = __builtin_elementwise_max(
                        acc[nb][k], __builtin_elementwise_fma(qq, m0.h[k], b0.h[k]));
                    acc[nb][k] = __builtin_elementwise_max(
                        acc[nb][k], __builtin_elementwise_fma(qq, m1.h[k], b1.h[k]));
                }
            }
        }

        // stage partials: vw = distinct 32-h subset, j32 owns w = j32*8..+7
        const int vw  = wave * 2 + (lane >> 5);
        const int j32 = lane & 31;
#pragma unroll
        for (int nb = 0; nb < NB; ++nb) {
            H8 st;
            st.h[0] = acc[nb][0]; st.h[1] = acc[nb][1];
            st.h[2] = acc[nb][2]; st.h[3] = acc[nb][3];
            *(uint4*)&part[vw][nb][j32 * 4] = st.u;
        }
        __syncthreads();

        // reduce: thread t -> nb = t>>5 (0..7), j = t&31 (w block j*8..+7)
        {
            const int nb = t >> 5;
            const int j  = t & 31;
            H8 v; v.u = *(const uint4*)&part[0][nb][j * 4];
#pragma unroll
            for (int s2 = 1; s2 < 8; ++s2) {
                H8 w2; w2.u = *(const uint4*)&part[s2][nb][j * 4];
#pragma unroll
                for (int k = 0; k < 4; ++k)
                    v.h[k] = __builtin_elementwise_max(v.h[k], w2.h[k]);
            }
            h2 mn = __builtin_elementwise_min(
                        __builtin_elementwise_min(v.h[0], v.h[1]),
                        __builtin_elementwise_min(v.h[2], v.h[3]));
            float r = fminf((float)mn.x, (float)mn.y);
#pragma unroll
            for (int off = 16; off > 0; off >>= 1)
                r = fminf(r, __shfl_xor(r, off, 32));   // min within 32-lane group
            if (j == 0) qs[nb] = r;
        }
        __syncthreads();
#pragma unroll
        for (int nb = 0; nb < NB; ++nb) {
            const _Float16 qh = (_Float16)qs[nb];
            q2[nb].x = qh; q2[nb].y = qh;
        }
        // part[] rewritten only after this barrier next depth -> safe
    }

    if (t < NB) out[br * NBATCH + bg * NB + t] = qs[t];
}

// ---------------------------------------------------------------------------
extern "C" void kernel_launch(void* const* d_in, const int* in_sizes, int n_in,
                              void* d_out, int out_size, void* d_ws, size_t ws_size,
                              hipStream_t stream) {
    const float* val = (const float*)d_in[0];
    const float* M1  = (const float*)d_in[1];
    const float* B1  = (const float*)d_in[2];
    const float* M2  = (const float*)d_in[3];
    const float* B2  = (const float*)d_in[4];
    float*    out = (float*)d_out;
    _Float16* wsh = (_Float16*)d_ws;   // 4 MiB + over-read pad (ws >= 8 MiB, R2)

    transpose_half_k<<<dim3(512), dim3(256), 0, stream>>>(M1, B1, M2, B2, wsh);
    prop_h_k<<<dim3(256), dim3(256), 0, stream>>>(wsh, val, out);
}